// Round 1
// baseline (481.813 us; speedup 1.0000x reference)
//
#include <hip/hip_runtime.h>

// MoE fp32: route top-2 -> gather -> bf16 MFMA GEMMs.
// v2: weights are pre-transposed+converted to bf16 (n,k)-major by a streaming
// pass (wconv_k) so both GEMM operands stage as K-contiguous uint4 loads.
// One 67MB scratch holds w1T, then is overwritten with w2T between GEMMs.

typedef __bf16 bf16;
typedef __bf16 bf16x8 __attribute__((ext_vector_type(8)));
typedef float floatx4 __attribute__((ext_vector_type(4)));

#define T_TOK 1024
#define HID 1024
#define FFN 4096
#define NEXP 8
#define BM 128
#define BN 128
#define BK 32
#define LP 36   // LDS row stride (bf16) = 18 dwords: conflict-free b128 r/w

// ---------------- x -> bf16 ----------------
__global__ void xconv_k(const float* __restrict__ x, bf16* __restrict__ xb) {
  int i = blockIdx.x * 256 + threadIdx.x;  // 8 elems each
  float4 a = ((const float4*)x)[i * 2];
  float4 b = ((const float4*)x)[i * 2 + 1];
  bf16 t[8] = {(bf16)a.x, (bf16)a.y, (bf16)a.z, (bf16)a.w,
               (bf16)b.x, (bf16)b.y, (bf16)b.z, (bf16)b.w};
  *(bf16x8*)&xb[(size_t)i * 8] = *(bf16x8*)t;
}

// ---------------- w (E,K,N) f32 -> wT (E,N,K) bf16 ----------------
// Thread: one (e, n, kc). Reads 32 k-strided floats (lane-coalesced along n),
// writes 64B contiguous bf16. Pure streaming, 32 loads in flight per thread.
__global__ void wconv_k(const float* __restrict__ w, bf16* __restrict__ wt,
                        int K, int N, int lgN, int lgKC) {
  int gid = blockIdx.x * 256 + threadIdx.x;
  int n = gid & (N - 1);
  int kc = (gid >> lgN) & ((K >> 5) - 1);
  int e = gid >> (lgN + lgKC);
  const float* src = w + ((size_t)e * K + (size_t)kc * 32) * N + n;
  bf16* dst = wt + ((size_t)e * N + n) * (size_t)K + kc * 32;
  float v[32];
#pragma unroll
  for (int j = 0; j < 32; j++) v[j] = src[(size_t)j * N];
  bf16x8 pk[4];
#pragma unroll
  for (int q = 0; q < 4; q++)
#pragma unroll
    for (int i = 0; i < 8; i++) pk[q][i] = (bf16)v[q * 8 + i];
#pragma unroll
  for (int q = 0; q < 4; q++) *(bf16x8*)(dst + q * 8) = pk[q];
}

// ---------------- Router ----------------
__global__ void router_k(const float* __restrict__ x, const float* __restrict__ gw,
                         const float* __restrict__ gb, int* __restrict__ cnt,
                         int* __restrict__ elist, float* __restrict__ ewt) {
  int wave = threadIdx.x >> 6;
  int lane = threadIdx.x & 63;
  int t = blockIdx.x * 4 + wave;
  const float* xr = x + (size_t)t * HID;
  float xv[16];
#pragma unroll
  for (int j = 0; j < 16; j++) xv[j] = xr[lane + 64 * j];
  float logits[NEXP];
#pragma unroll
  for (int e = 0; e < NEXP; e++) {
    const float* g = gw + (size_t)e * HID;
    float s = 0.f;
#pragma unroll
    for (int j = 0; j < 16; j++) s += xv[j] * g[lane + 64 * j];
#pragma unroll
    for (int off = 32; off; off >>= 1) s += __shfl_xor(s, off, 64);
    logits[e] = s + gb[e];
  }
  int i0 = 0; float l0 = logits[0];
#pragma unroll
  for (int e = 1; e < NEXP; e++) if (logits[e] > l0) { l0 = logits[e]; i0 = e; }
  int i1 = -1; float l1 = -3.0e38f;
#pragma unroll
  for (int e = 0; e < NEXP; e++) if (e != i0 && logits[e] > l1) { l1 = logits[e]; i1 = e; }
  if (lane == 0) {
    float w0 = 1.f / (1.f + expf(l1 - l0));
    float w1 = 1.f - w0;
    int p0 = atomicAdd(cnt + i0, 1);
    elist[i0 * T_TOK + p0] = t * 2 + 0; ewt[i0 * T_TOK + p0] = w0;
    int p1 = atomicAdd(cnt + i1, 1);
    elist[i1 * T_TOK + p1] = t * 2 + 1; ewt[i1 * T_TOK + p1] = w1;
  }
}

// ---------------- GEMM1: h = gelu(Xg @ w1 + b1) ----------------
// A: gathered xb rows (bf16, K-contig). B: w1T rows (bf16, K-contig).
__global__ __launch_bounds__(256)
void gemm1_k(const bf16* __restrict__ xb, const bf16* __restrict__ w1t,
             const float* __restrict__ b1, const int* __restrict__ cnt,
             const int* __restrict__ elist, bf16* __restrict__ hbuf) {
  int e = blockIdx.z;
  int c = cnt[e];
  int m0 = blockIdx.y * BM;
  if (m0 >= c) return;
  int n0 = blockIdx.x * BN;

  __shared__ __align__(16) bf16 As[BM][LP];
  __shared__ __align__(16) bf16 Bs[BN][LP];

  int tid = threadIdx.x;
  int ar = tid >> 1;
  int ac = (tid & 1) * 16;
  int ra = m0 + ar; if (ra >= c) ra = c - 1;
  const bf16* aptr = xb + (size_t)(elist[e * T_TOK + ra] >> 1) * HID + ac;
  const bf16* bptr = w1t + (size_t)e * FFN * HID + (size_t)(n0 + ar) * HID + ac;

  uint4 a0, a1, b0, b1r;
  a0 = *(const uint4*)(aptr);
  a1 = *(const uint4*)(aptr + 8);
  b0 = *(const uint4*)(bptr);
  b1r = *(const uint4*)(bptr + 8);

  floatx4 acc[4][4] = {};
  int ln = tid & 63, wv = tid >> 6;
  int fm = ln & 15, quad = ln >> 4;
  int wm = (wv & 1) * 64, wn = (wv >> 1) * 64;

  for (int t = 0; t < HID / BK; t++) {
    uint4 wa0 = a0, wa1 = a1, wb0 = b0, wb1 = b1r;
    __syncthreads();                       // frag reads of tile t-1 done
    *(uint4*)&As[ar][ac]     = wa0;
    *(uint4*)&As[ar][ac + 8] = wa1;
    *(uint4*)&Bs[ar][ac]     = wb0;
    *(uint4*)&Bs[ar][ac + 8] = wb1;
    if (t + 1 < HID / BK) {                // prefetch t+1: in flight across MFMAs
      aptr += BK;
      bptr += BK;
      a0 = *(const uint4*)(aptr);
      a1 = *(const uint4*)(aptr + 8);
      b0 = *(const uint4*)(bptr);
      b1r = *(const uint4*)(bptr + 8);
    }
    __syncthreads();                       // writes visible
    bf16x8 af[4], bfr[4];
#pragma unroll
    for (int i = 0; i < 4; i++) af[i] = *(const bf16x8*)&As[wm + i * 16 + fm][quad * 8];
#pragma unroll
    for (int j = 0; j < 4; j++) bfr[j] = *(const bf16x8*)&Bs[wn + j * 16 + fm][quad * 8];
#pragma unroll
    for (int i = 0; i < 4; i++)
#pragma unroll
      for (int j = 0; j < 4; j++)
        acc[i][j] = __builtin_amdgcn_mfma_f32_16x16x32_bf16(af[i], bfr[j], acc[i][j], 0, 0, 0);
  }

  const float* b1e = b1 + (size_t)e * FFN;
#pragma unroll
  for (int i = 0; i < 4; i++) {
    int rb = m0 + wm + i * 16 + quad * 4;
#pragma unroll
    for (int j = 0; j < 4; j++) {
      int col = n0 + wn + j * 16 + fm;
      float bias = b1e[col];
#pragma unroll
      for (int r = 0; r < 4; r++) {
        int row = rb + r;
        if (row < c) {
          int slot = elist[e * T_TOK + row];
          float v = acc[i][j][r] + bias;
          float g = 0.5f * v * (1.f + erff(v * 0.70710678118654752f));
          hbuf[(size_t)slot * FFN + col] = (bf16)g;
        }
      }
    }
  }
}

// ---------------- GEMM2 split-K=4: part[ks][slot] = wt*(h @ w2 + b2?) ----------------
__global__ __launch_bounds__(256)
void gemm2_k(const bf16* __restrict__ hbuf, const bf16* __restrict__ w2t,
             const float* __restrict__ b2, const int* __restrict__ cnt,
             const int* __restrict__ elist, const float* __restrict__ ewt,
             float* __restrict__ part) {
  int e = blockIdx.z & 7;
  int ks = blockIdx.z >> 3;
  int c = cnt[e];
  int m0 = blockIdx.y * BM;
  if (m0 >= c) return;
  int n0 = blockIdx.x * BN;
  int kbeg = ks * (FFN / 4);

  __shared__ __align__(16) bf16 As[BM][LP];
  __shared__ __align__(16) bf16 Bs[BN][LP];

  int tid = threadIdx.x;
  int ar = tid >> 1;
  int ac = (tid & 1) * 16;
  int ra = m0 + ar; if (ra >= c) ra = c - 1;
  const bf16* aptr = hbuf + (size_t)elist[e * T_TOK + ra] * FFN + kbeg + ac;
  const bf16* bptr = w2t + (size_t)e * HID * FFN + (size_t)(n0 + ar) * FFN + kbeg + ac;

  uint4 a0, a1, b0, b1r;
  a0 = *(const uint4*)(aptr);
  a1 = *(const uint4*)(aptr + 8);
  b0 = *(const uint4*)(bptr);
  b1r = *(const uint4*)(bptr + 8);

  floatx4 acc[4][4] = {};
  int ln = tid & 63, wv = tid >> 6;
  int fm = ln & 15, quad = ln >> 4;
  int wm = (wv & 1) * 64, wn = (wv >> 1) * 64;

  const int NT = (FFN / 4) / BK;
  for (int t = 0; t < NT; t++) {
    uint4 wa0 = a0, wa1 = a1, wb0 = b0, wb1 = b1r;
    __syncthreads();
    *(uint4*)&As[ar][ac]     = wa0;
    *(uint4*)&As[ar][ac + 8] = wa1;
    *(uint4*)&Bs[ar][ac]     = wb0;
    *(uint4*)&Bs[ar][ac + 8] = wb1;
    if (t + 1 < NT) {
      aptr += BK;
      bptr += BK;
      a0 = *(const uint4*)(aptr);
      a1 = *(const uint4*)(aptr + 8);
      b0 = *(const uint4*)(bptr);
      b1r = *(const uint4*)(bptr + 8);
    }
    __syncthreads();
    bf16x8 af[4], bfr[4];
#pragma unroll
    for (int i = 0; i < 4; i++) af[i] = *(const bf16x8*)&As[wm + i * 16 + fm][quad * 8];
#pragma unroll
    for (int j = 0; j < 4; j++) bfr[j] = *(const bf16x8*)&Bs[wn + j * 16 + fm][quad * 8];
#pragma unroll
    for (int i = 0; i < 4; i++)
#pragma unroll
      for (int j = 0; j < 4; j++)
        acc[i][j] = __builtin_amdgcn_mfma_f32_16x16x32_bf16(af[i], bfr[j], acc[i][j], 0, 0, 0);
  }

  const float* b2e = b2 + (size_t)e * HID;
#pragma unroll
  for (int i = 0; i < 4; i++) {
    int rb = m0 + wm + i * 16 + quad * 4;
#pragma unroll
    for (int j = 0; j < 4; j++) {
      int col = n0 + wn + j * 16 + fm;
      float bias = (ks == 0) ? b2e[col] : 0.f;
#pragma unroll
      for (int r = 0; r < 4; r++) {
        int row = rb + r;
        if (row < c) {
          int slot = elist[e * T_TOK + row];
          float w = ewt[e * T_TOK + row];
          part[((size_t)ks * (2 * T_TOK) + slot) * HID + col] = w * (acc[i][j][r] + bias);
        }
      }
    }
  }
}

// ---------------- Combine ----------------
__global__ void combine_k(const float* __restrict__ part, float* __restrict__ out) {
  int i = blockIdx.x * 256 + threadIdx.x;
  int t = i >> 8;
  int h4 = (i & 255) * 4;
  float4 s = {0.f, 0.f, 0.f, 0.f};
#pragma unroll
  for (int ks = 0; ks < 4; ks++)
#pragma unroll
    for (int sl = 0; sl < 2; sl++) {
      float4 v = *(const float4*)&part[((size_t)ks * (2 * T_TOK) + t * 2 + sl) * HID + h4];
      s.x += v.x; s.y += v.y; s.z += v.z; s.w += v.w;
    }
  *(float4*)&out[(size_t)t * HID + h4] = s;
}

extern "C" void kernel_launch(void* const* d_in, const int* in_sizes, int n_in,
                              void* d_out, int out_size, void* d_ws, size_t ws_size,
                              hipStream_t stream) {
  const float* x  = (const float*)d_in[0];
  const float* gw = (const float*)d_in[1];
  const float* gb = (const float*)d_in[2];
  const float* w1 = (const float*)d_in[3];
  const float* b1 = (const float*)d_in[4];
  const float* w2 = (const float*)d_in[5];
  const float* b2 = (const float*)d_in[6];
  float* out = (float*)d_out;

  char* ws = (char*)d_ws;
  int*   cnt   = (int*)ws;                                   // 32 B
  int*   elist = (int*)(ws + 1024);                          // 32 KB
  float* ewt   = (float*)(ws + 1024 + 32768);                // 32 KB
  bf16*  xb    = (bf16*)(ws + (1 << 16));                    // 2 MB
  bf16*  hbuf  = (bf16*)(ws + ((size_t)4 << 20));            // 16.8 MB
  float* part  = (float*)(ws + ((size_t)21 << 20));          // 33.6 MB
  bf16*  wT    = (bf16*)(ws + ((size_t)55 << 20));           // 67.1 MB (shared by w1T then w2T)

  hipMemsetAsync(cnt, 0, 32, stream);
  xconv_k<<<512, 256, 0, stream>>>(x, xb);
  router_k<<<T_TOK / 4, 256, 0, stream>>>(x, gw, gb, cnt, elist, ewt);
  // w1 (E, HID=1024 k, FFN=4096 n) -> wT (E, 4096, 1024)
  wconv_k<<<4096, 256, 0, stream>>>(w1, wT, HID, FFN, 12, 5);
  gemm1_k<<<dim3(FFN / BN, 8, NEXP), 256, 0, stream>>>(xb, wT, b1, cnt, elist, hbuf);
  // w2 (E, FFN=4096 k, HID=1024 n) -> wT (E, 1024, 4096)
  wconv_k<<<4096, 256, 0, stream>>>(w2, wT, FFN, HID, 10, 7);
  gemm2_k<<<dim3(HID / BN, 8, NEXP * 4), 256, 0, stream>>>(hbuf, wT, b2, cnt, elist, ewt, part);
  combine_k<<<(T_TOK * HID / 4) / 256, 256, 0, stream>>>(part, out);
}

// Round 3
// 445.196 us; speedup vs baseline: 1.0822x; 1.0822x over previous
//
#include <hip/hip_runtime.h>

// MoE fp32: route top-2 -> gather -> bf16 MFMA GEMMs.
// v3 (resubmit; round-2 failure was container infra, not kernel):
// no weight pre-pass (fp32 weights read directly ONCE, convert in staging,
// LLC absorbs the m-block re-read). BN=64 doubles live blocks -> 4+ blocks/CU
// (16-24 waves/CU) to hide load latency by TLP. gemm2 fuses the combine via
// fp32 atomicAdd into out (out memset in-graph), removing `part` entirely.

typedef __bf16 bf16;
typedef __bf16 bf16x8 __attribute__((ext_vector_type(8)));
typedef float floatx4 __attribute__((ext_vector_type(4)));

#define T_TOK 1024
#define HID 1024
#define FFN 4096
#define NEXP 8
#define BM 128
#define BN 64
#define BK 32
#define LP 36   // LDS row stride (bf16): conflict-free b128 r/w

// ---------------- x -> bf16 ----------------
__global__ void xconv_k(const float* __restrict__ x, bf16* __restrict__ xb) {
  int i = blockIdx.x * 256 + threadIdx.x;  // 8 elems each
  float4 a = ((const float4*)x)[i * 2];
  float4 b = ((const float4*)x)[i * 2 + 1];
  bf16 t[8] = {(bf16)a.x, (bf16)a.y, (bf16)a.z, (bf16)a.w,
               (bf16)b.x, (bf16)b.y, (bf16)b.z, (bf16)b.w};
  *(bf16x8*)&xb[(size_t)i * 8] = *(bf16x8*)t;
}

// ---------------- Router ----------------
__global__ void router_k(const float* __restrict__ x, const float* __restrict__ gw,
                         const float* __restrict__ gb, int* __restrict__ cnt,
                         int* __restrict__ elist, float* __restrict__ ewt) {
  int wave = threadIdx.x >> 6;
  int lane = threadIdx.x & 63;
  int t = blockIdx.x * 4 + wave;
  const float* xr = x + (size_t)t * HID;
  float xv[16];
#pragma unroll
  for (int j = 0; j < 16; j++) xv[j] = xr[lane + 64 * j];
  float logits[NEXP];
#pragma unroll
  for (int e = 0; e < NEXP; e++) {
    const float* g = gw + (size_t)e * HID;
    float s = 0.f;
#pragma unroll
    for (int j = 0; j < 16; j++) s += xv[j] * g[lane + 64 * j];
#pragma unroll
    for (int off = 32; off; off >>= 1) s += __shfl_xor(s, off, 64);
    logits[e] = s + gb[e];
  }
  int i0 = 0; float l0 = logits[0];
#pragma unroll
  for (int e = 1; e < NEXP; e++) if (logits[e] > l0) { l0 = logits[e]; i0 = e; }
  int i1 = -1; float l1 = -3.0e38f;
#pragma unroll
  for (int e = 0; e < NEXP; e++) if (e != i0 && logits[e] > l1) { l1 = logits[e]; i1 = e; }
  if (lane == 0) {
    float w0 = 1.f / (1.f + expf(l1 - l0));
    float w1 = 1.f - w0;
    int p0 = atomicAdd(cnt + i0, 1);
    elist[i0 * T_TOK + p0] = t * 2 + 0; ewt[i0 * T_TOK + p0] = w0;
    int p1 = atomicAdd(cnt + i1, 1);
    elist[i1 * T_TOK + p1] = t * 2 + 1; ewt[i1 * T_TOK + p1] = w1;
  }
}

// ---------------- GEMM1: h = gelu(Xg @ w1 + b1) ----------------
// A: gathered xb rows (bf16, K-contig). B: w1[e] fp32 (k,n) read direct,
// 8 k-strided coalesced dwords/thread, convert, one b128 LDS write.
__global__ __launch_bounds__(256)
void gemm1_k(const bf16* __restrict__ xb, const float* __restrict__ w1,
             const float* __restrict__ b1, const int* __restrict__ cnt,
             const int* __restrict__ elist, bf16* __restrict__ hbuf) {
  int e = blockIdx.z;
  int c = cnt[e];
  int m0 = blockIdx.y * BM;
  if (m0 >= c) return;
  int n0 = blockIdx.x * BN;

  __shared__ __align__(16) bf16 As[BM][LP];
  __shared__ __align__(16) bf16 Bs[BN][LP];

  int tid = threadIdx.x;
  int ar = tid >> 1;
  int ac = (tid & 1) * 16;
  int ra = m0 + ar; if (ra >= c) ra = c - 1;
  const bf16* aptr = xb + (size_t)(elist[e * T_TOK + ra] >> 1) * HID + ac;
  int bn = tid & 63;
  int bk = (tid >> 6) * 8;
  const float* bptr = w1 + (size_t)e * HID * FFN + (size_t)bk * FFN + n0 + bn;

  uint4 a0, a1;
  float bfl[8];
  a0 = *(const uint4*)(aptr);
  a1 = *(const uint4*)(aptr + 8);
#pragma unroll
  for (int j = 0; j < 8; j++) bfl[j] = bptr[(size_t)j * FFN];

  floatx4 acc[4][2] = {};
  int ln = tid & 63, wv = tid >> 6;
  int fm = ln & 15, quad = ln >> 4;
  int wm = (wv & 1) * 64, wn = (wv >> 1) * 32;

  for (int t = 0; t < HID / BK; t++) {
    bf16 bb[8];
#pragma unroll
    for (int j = 0; j < 8; j++) bb[j] = (bf16)bfl[j];
    uint4 wa0 = a0, wa1 = a1;
    __syncthreads();                       // frag reads of tile t-1 done
    *(uint4*)&As[ar][ac]     = wa0;
    *(uint4*)&As[ar][ac + 8] = wa1;
    *(bf16x8*)&Bs[bn][bk]    = *(bf16x8*)&bb[0];
    if (t + 1 < HID / BK) {                // prefetch t+1: in flight across MFMAs
      aptr += BK;
      a0 = *(const uint4*)(aptr);
      a1 = *(const uint4*)(aptr + 8);
      bptr += (size_t)BK * FFN;
#pragma unroll
      for (int j = 0; j < 8; j++) bfl[j] = bptr[(size_t)j * FFN];
    }
    __syncthreads();                       // writes visible
    bf16x8 af[4], bfr[2];
#pragma unroll
    for (int i = 0; i < 4; i++) af[i] = *(const bf16x8*)&As[wm + i * 16 + fm][quad * 8];
#pragma unroll
    for (int j = 0; j < 2; j++) bfr[j] = *(const bf16x8*)&Bs[wn + j * 16 + fm][quad * 8];
#pragma unroll
    for (int i = 0; i < 4; i++)
#pragma unroll
      for (int j = 0; j < 2; j++)
        acc[i][j] = __builtin_amdgcn_mfma_f32_16x16x32_bf16(af[i], bfr[j], acc[i][j], 0, 0, 0);
  }

  const float* b1e = b1 + (size_t)e * FFN;
#pragma unroll
  for (int i = 0; i < 4; i++) {
    int rb = m0 + wm + i * 16 + quad * 4;
#pragma unroll
    for (int j = 0; j < 2; j++) {
      int col = n0 + wn + j * 16 + fm;
      float bias = b1e[col];
#pragma unroll
      for (int r = 0; r < 4; r++) {
        int row = rb + r;
        if (row < c) {
          int slot = elist[e * T_TOK + row];
          float v = acc[i][j][r] + bias;
          float g = 0.5f * v * (1.f + erff(v * 0.70710678118654752f));
          hbuf[(size_t)slot * FFN + col] = (bf16)g;
        }
      }
    }
  }
}

// ---------------- GEMM2 split-K=4, fused combine: out += wt*(h @ w2 + b2?) ----------------
__global__ __launch_bounds__(256)
void gemm2_k(const bf16* __restrict__ hbuf, const float* __restrict__ w2,
             const float* __restrict__ b2, const int* __restrict__ cnt,
             const int* __restrict__ elist, const float* __restrict__ ewt,
             float* __restrict__ out) {
  int e = blockIdx.z & 7;
  int ks = blockIdx.z >> 3;
  int c = cnt[e];
  int m0 = blockIdx.y * BM;
  if (m0 >= c) return;
  int n0 = blockIdx.x * BN;
  int kbeg = ks * (FFN / 4);

  __shared__ __align__(16) bf16 As[BM][LP];
  __shared__ __align__(16) bf16 Bs[BN][LP];

  int tid = threadIdx.x;
  int ar = tid >> 1;
  int ac = (tid & 1) * 16;
  int ra = m0 + ar; if (ra >= c) ra = c - 1;
  const bf16* aptr = hbuf + (size_t)elist[e * T_TOK + ra] * FFN + kbeg + ac;
  int bn = tid & 63;
  int bk = (tid >> 6) * 8;
  const float* bptr = w2 + (size_t)e * FFN * HID + (size_t)(kbeg + bk) * HID + n0 + bn;

  uint4 a0, a1;
  float bfl[8];
  a0 = *(const uint4*)(aptr);
  a1 = *(const uint4*)(aptr + 8);
#pragma unroll
  for (int j = 0; j < 8; j++) bfl[j] = bptr[(size_t)j * HID];

  floatx4 acc[4][2] = {};
  int ln = tid & 63, wv = tid >> 6;
  int fm = ln & 15, quad = ln >> 4;
  int wm = (wv & 1) * 64, wn = (wv >> 1) * 32;

  const int NT = (FFN / 4) / BK;
  for (int t = 0; t < NT; t++) {
    bf16 bb[8];
#pragma unroll
    for (int j = 0; j < 8; j++) bb[j] = (bf16)bfl[j];
    uint4 wa0 = a0, wa1 = a1;
    __syncthreads();
    *(uint4*)&As[ar][ac]     = wa0;
    *(uint4*)&As[ar][ac + 8] = wa1;
    *(bf16x8*)&Bs[bn][bk]    = *(bf16x8*)&bb[0];
    if (t + 1 < NT) {
      aptr += BK;
      a0 = *(const uint4*)(aptr);
      a1 = *(const uint4*)(aptr + 8);
      bptr += (size_t)BK * HID;
#pragma unroll
      for (int j = 0; j < 8; j++) bfl[j] = bptr[(size_t)j * HID];
    }
    __syncthreads();
    bf16x8 af[4], bfr[2];
#pragma unroll
    for (int i = 0; i < 4; i++) af[i] = *(const bf16x8*)&As[wm + i * 16 + fm][quad * 8];
#pragma unroll
    for (int j = 0; j < 2; j++) bfr[j] = *(const bf16x8*)&Bs[wn + j * 16 + fm][quad * 8];
#pragma unroll
    for (int i = 0; i < 4; i++)
#pragma unroll
      for (int j = 0; j < 2; j++)
        acc[i][j] = __builtin_amdgcn_mfma_f32_16x16x32_bf16(af[i], bfr[j], acc[i][j], 0, 0, 0);
  }

  const float* b2e = b2 + (size_t)e * HID;
#pragma unroll
  for (int i = 0; i < 4; i++) {
    int rb = m0 + wm + i * 16 + quad * 4;
#pragma unroll
    for (int j = 0; j < 2; j++) {
      int col = n0 + wn + j * 16 + fm;
      float bias = (ks == 0) ? b2e[col] : 0.f;
#pragma unroll
      for (int r = 0; r < 4; r++) {
        int row = rb + r;
        if (row < c) {
          int slot = elist[e * T_TOK + row];
          float w = ewt[e * T_TOK + row];
          atomicAdd(&out[(size_t)(slot >> 1) * HID + col], w * (acc[i][j][r] + bias));
        }
      }
    }
  }
}

extern "C" void kernel_launch(void* const* d_in, const int* in_sizes, int n_in,
                              void* d_out, int out_size, void* d_ws, size_t ws_size,
                              hipStream_t stream) {
  const float* x  = (const float*)d_in[0];
  const float* gw = (const float*)d_in[1];
  const float* gb = (const float*)d_in[2];
  const float* w1 = (const float*)d_in[3];
  const float* b1 = (const float*)d_in[4];
  const float* w2 = (const float*)d_in[5];
  const float* b2 = (const float*)d_in[6];
  float* out = (float*)d_out;

  char* ws = (char*)d_ws;
  int*   cnt   = (int*)ws;                                   // 32 B
  int*   elist = (int*)(ws + 1024);                          // 32 KB
  float* ewt   = (float*)(ws + 1024 + 32768);                // 32 KB
  bf16*  xb    = (bf16*)(ws + (1 << 16));                    // 2 MB
  bf16*  hbuf  = (bf16*)(ws + ((size_t)4 << 20));            // 16.8 MB

  hipMemsetAsync(cnt, 0, 32, stream);
  hipMemsetAsync(out, 0, out_size, stream);
  xconv_k<<<512, 256, 0, stream>>>(x, xb);
  router_k<<<T_TOK / 4, 256, 0, stream>>>(x, gw, gb, cnt, elist, ewt);
  gemm1_k<<<dim3(FFN / BN, T_TOK / BM, NEXP), 256, 0, stream>>>(xb, w1, b1, cnt, elist, hbuf);
  gemm2_k<<<dim3(HID / BN, T_TOK / BM, NEXP * 4), 256, 0, stream>>>(hbuf, w2, b2, cnt, elist, ewt, out);
}